// Round 5
// baseline (337.034 us; speedup 1.0000x reference)
//
#include <hip/hip_runtime.h>

// Problem constants
#define B 8
#define N 4096
#define C 128
#define C2 256          // K-dim of fused GEMM: [ptl | s]
#define KNN 21          // top-(K+1), drop nearest
#define CAP 22          // per-lane append buffer capacity (slots 0..21)

typedef unsigned long long u64;
typedef unsigned int u32;
typedef unsigned short u16;

typedef __attribute__((ext_vector_type(8))) short bf16x8;
typedef __attribute__((ext_vector_type(4))) float f32x4;

__device__ __forceinline__ float bf2f(u16 u) {
    return __uint_as_float(((u32)u) << 16);
}
__device__ __forceinline__ u16 f2bf(float f) {  // round-to-nearest-even
    u32 x = __float_as_uint(f);
    return (u16)((x + 0x7FFFu + ((x >> 16) & 1u)) >> 16);
}

// ---------------------------------------------------------------------------
// K1: transpose + leaky_relu: points (B,C,N) f32 -> X[b][n][c] (c<128) bf16.
// Also prepacks cand[b][m] = float4(x, y, z, sq_norm) once per point (same
// __fmul_rn/__fadd_rn sequence the KNN staging used inline -> bit-identical).
// ---------------------------------------------------------------------------
__global__ __launch_bounds__(256) void k_transpose_lrelu(
        const float* __restrict__ pts, u16* __restrict__ X,
        const float* __restrict__ xyz, float4* __restrict__ cand) {
    __shared__ u16 tile[32][33];
    int b  = blockIdx.z;
    int c0 = blockIdx.y * 32;
    int n0 = blockIdx.x * 32;
    int tx = threadIdx.x, ty = threadIdx.y;   // 32 x 8

    if (blockIdx.y == 0 && ty == 0) {         // prepack: 32 lanes, 32 points
        int n = n0 + tx;
        const float* xz = xyz + (size_t)b * 3 * N;
        float x = xz[n], y = xz[N + n], z = xz[2 * N + n];
        float sn = __fadd_rn(__fadd_rn(__fmul_rn(x, x), __fmul_rn(y, y)),
                             __fmul_rn(z, z));
        cand[(size_t)b * N + n] = make_float4(x, y, z, sn);
    }

    const float* src = pts + (size_t)b * C * N;
    #pragma unroll
    for (int i = 0; i < 32; i += 8) {
        float v = src[(size_t)(c0 + ty + i) * N + n0 + tx];
        if (v < 0.f) v = __fmul_rn(v, 0.01f);
        tile[ty + i][tx] = f2bf(v);
    }
    __syncthreads();
    u16* dst = X + (size_t)b * N * C2;
    #pragma unroll
    for (int i = 0; i < 32; i += 8) {
        dst[(size_t)(n0 + ty + i) * C2 + (c0 + tx)] = tile[tx][ty + i];
    }
}

// ---------------------------------------------------------------------------
// K2: exact KNN (top-21 by (sq, idx), drop min) + neighbor-feature gather-sum.
// r3 structure (S=4: wave w scans [w*1024,+1024), per-candidate loop, CAP 22,
// trigger 15, merge, gather identical) + two grafts:
//  (a) FLOAT KEYS: the 3-instr sortable-u32 transform leaves the per-candidate
//      path; selection compares raw f32 (strict compares keep the in-wave
//      scan-order tie-break); transform applied to the 21 survivors at
//      merge-pack -> bit-identical u64s to r3's merge.
//  (b) SHARED CROSS-WAVE THRESHOLD: each wave publishes its key[20] per query
//      to sthr[4][64] after every compact; scan additionally rejects
//      sq > min(other waves' 21st)  (tie-SAFE: '<=' keeps cross-wave equal
//      keys, which a lower-index range could legitimately win; own threshold
//      stays strict '<' since in-wave later idx always loses ties).
//      An element >= some wave's current 21st has >=21 union elements ahead
//      -> provably not in union top-21 -> safe to drop. Stale reads are
//      conservative (thresholds only decrease) -> no barrier; volatile LDS
//      reads prevent hoisting. Cuts per-query insertions ~412 -> ~230; compact
//      (~55% of VALU work, 0.18us/insertion measured from r0 vs r4) shrinks.
// ---------------------------------------------------------------------------
__global__ __launch_bounds__(256) void k_knn_gather(
        const float4* __restrict__ cand, u16* __restrict__ X) {
    __shared__ __align__(16) char lds[52224];
    float4* stg  = (float4*)lds;                      // [4][288]  18432 B
    u32*    kbuf = (u32*)(lds + 18432);               // [CAP][256] 22528 B
    u16*    ibuf = (u16*)(lds + 18432 + 22528);       // [CAP][256] 11264 B
    u64*    mg   = (u64*)lds;                         // [256][21]  43008 B (phase B)
    __shared__ u16 win[64 * KNN];
    __shared__ float sthr[4][64];                     // per-(wave,query) 21st key

    int tid = threadIdx.x;
    int w = tid >> 6, l = tid & 63;
    int b = blockIdx.y;
    int n0 = blockIdx.x * 64;
    int nq = n0 + l;

    const float4* candb = cand + (size_t)b * N;
    float4 cq = candb[nq];                            // query point (coalesced)
    float qx = cq.x, qy = cq.y, qz = cq.z, snq = cq.w;

    float key[KNN];
    u32 idx[KNN];
    #pragma unroll
    for (int i = 0; i < KNN; ++i) { key[i] = __builtin_inff(); idx[i] = 0u; }
    int cnt = 0;
    float thr = __builtin_inff();

    sthr[w][l] = __builtin_inff();                    // init shared thresholds
    __syncthreads();
    volatile float* vsthr = &sthr[0][0];              // force per-refresh reload

    auto compact = [&]() {
        #pragma unroll 1
        for (int i = 0; i < CAP; ++i) {
            if (__ballot(i < cnt) == 0ull) break;
            float kv = __uint_as_float(kbuf[i * 256 + tid]);
            u32 iv = ibuf[i * 256 + tid];
            bool ins = (i < cnt) && (kv < key[20]);   // strict: ties keep old
            if (__ballot(ins) != 0ull) {
                key[20] = ins ? kv : key[20];
                idx[20] = ins ? iv : idx[20];
                #pragma unroll
                for (int t = 19; t >= 0; --t) {       // stable bubble (strict >)
                    bool sw = key[t] > key[t + 1];
                    float ka = sw ? key[t + 1] : key[t];
                    float kz = sw ? key[t] : key[t + 1];
                    u32 ia = sw ? idx[t + 1] : idx[t];
                    u32 iz = sw ? idx[t] : idx[t + 1];
                    key[t] = ka; key[t + 1] = kz;
                    idx[t] = ia; idx[t + 1] = iz;
                }
            }
        }
        cnt = 0;
        thr = key[20];
        sthr[w][l] = key[20];                         // publish (race-benign)
    };

    float4* mystg = stg + w * 288;
    int wl = l + (l >> 3);                            // padded staging index
    int o1 = ((w + 1) & 3) * 64 + l;                  // other waves' slots
    int o2 = ((w + 2) & 3) * 64 + l;
    int o3 = ((w + 3) & 3) * 64 + l;

    for (int sc = 0; sc < 4; ++sc) {
        int m0 = w * 1024 + sc * 256;
        // stage 256 candidates from prepacked cand (coalesced float4)
        float4 v0 = candb[m0 + l];
        float4 v1 = candb[m0 + l + 64];
        float4 v2 = candb[m0 + l + 128];
        float4 v3 = candb[m0 + l + 192];
        mystg[wl]       = v0;                         // conflict-free writes
        mystg[wl + 72]  = v1;
        mystg[wl + 144] = v2;
        mystg[wl + 216] = v3;
        asm volatile("s_waitcnt lgkmcnt(0)" ::: "memory");
        for (int cc = 0; cc < 256; cc += 8) {
            int base = cc + (cc >> 3);                // wave-uniform padded base
            float smin = fminf(fminf(vsthr[o1], vsthr[o2]), vsthr[o3]);
            #pragma unroll
            for (int j = 0; j < 8; ++j) {
                float4 cp = mystg[base + j];          // wave-broadcast read
                int m = m0 + cc + j;
                float dot = __fadd_rn(__fadd_rn(__fmul_rn(qx, cp.x),
                                                __fmul_rn(qy, cp.y)),
                                      __fmul_rn(qz, cp.z));
                float sq = __fadd_rn(__fsub_rn(snq, __fadd_rn(dot, dot)), cp.w);
                kbuf[cnt * 256 + tid] = __float_as_uint(sq);  // uncond append
                ibuf[cnt * 256 + tid] = (u16)m;
                cnt += ((sq < thr) && (sq <= smin));  // own strict, shared <=
            }
            if (__ballot(cnt >= 15) != 0ull) compact();
        }
    }
    compact();

    __syncthreads();                                  // phase-A buffers dead
    #pragma unroll
    for (int j = 0; j < KNN; ++j) {                   // monotone f32 -> u32
        u32 bits = __float_as_uint(key[j]);
        u32 kb2 = bits ^ (0x80000000u | (u32)(((int)bits) >> 31));
        mg[(w * 64 + l) * KNN + j] = ((u64)kb2 << 32) | (u64)idx[j];
    }
    __syncthreads();

    if (w == 0) {                                     // 4-way merge per query
        int p0 = 0, p1 = 0, p2 = 0, p3 = 0;
        for (int j = 0; j < KNN; ++j) {
            u64 c0 = mg[(0 * 64 + l) * KNN + p0];
            u64 c1 = mg[(1 * 64 + l) * KNN + p1];
            u64 c2 = mg[(2 * 64 + l) * KNN + p2];
            u64 c3 = mg[(3 * 64 + l) * KNN + p3];
            u64 m01 = c0 < c1 ? c0 : c1; int s01 = c0 < c1 ? 0 : 1;
            u64 m23 = c2 < c3 ? c2 : c3; int s23 = c2 < c3 ? 2 : 3;
            u64 mm = m01 < m23 ? m01 : m23;
            int sel = m01 < m23 ? s01 : s23;
            win[l * KNN + j] = (u16)(mm & 0xFFFFu);
            p0 += (sel == 0); p1 += (sel == 1); p2 += (sel == 2); p3 += (sel == 3);
        }
    }
    __syncthreads();

    // gather-sum: wave w handles 16 queries; lane covers channels 2l, 2l+1
    const u16* Xb = X + (size_t)b * N * C2;
    for (int qq = 0; qq < 16; ++qq) {
        int q = w * 16 + qq;
        float f0 = 0.f, f1 = 0.f;
        #pragma unroll
        for (int j = 1; j < KNN; ++j) {               // skip nearest (j=0)
            int m = win[q * KNN + j];
            u32 u2 = *(const u32*)(Xb + (size_t)m * C2 + 2 * l);
            f0 += bf2f((u16)(u2 & 0xFFFFu));
            f1 += bf2f((u16)(u2 >> 16));
        }
        u16* dst = X + ((size_t)b * N + n0 + q) * C2 + 128 + 2 * l;
        *(u32*)dst = ((u32)f2bf(f1) << 16) | (u32)f2bf(f0);
    }
}

// ---------------------------------------------------------------------------
// K3: MFMA GEMM. out[b][o][n] = (W[o][:].X[b][n][:] + bc[o]+20bg[o])/21 + pts.
// Wave tile: 16(o) x 64(n), K=256 = 8 x mfma_f32_16x16x32_bf16 x 4 subtiles.
// XCD-pairing swizzle: the two blocks sharing an nt's 32KB X panel map to
// dispatch ids exactly 8 apart -> same XCD L2. bid -> (bid&7)*128 + (bid>>3).
// C/D map: col=lane&15 (n), row=(lane>>4)*4+reg (o)  [m89-verified]
// ---------------------------------------------------------------------------
__global__ __launch_bounds__(256) void k_gemm_mfma(
        const u16* __restrict__ X, const float* __restrict__ Wc,
        const float* __restrict__ Wg, const float* __restrict__ pts,
        const float* __restrict__ bc, const float* __restrict__ bg,
        float* __restrict__ out) {
    int lb = (blockIdx.x & 7) * 128 + (blockIdx.x >> 3);  // XCD-pairing swizzle
    int wid = lb * 4 + (threadIdx.x >> 6);   // 0..4095
    int lane = threadIdx.x & 63;
    int ot = wid & 7;            // 8 o-tiles of 16
    int nt = wid >> 3;           // 512 n-tiles of 64
    int b  = nt >> 6;            // 64 n-tiles per batch
    int n0 = (nt & 63) * 64;

    int l16 = lane & 15, lq = lane >> 4;
    const u16* Xb = X + (size_t)b * N * C2;
    const u16* bptr0 = Xb + (size_t)(n0 + 0 * 16 + l16) * C2 + lq * 8;
    const u16* bptr1 = Xb + (size_t)(n0 + 1 * 16 + l16) * C2 + lq * 8;
    const u16* bptr2 = Xb + (size_t)(n0 + 2 * 16 + l16) * C2 + lq * 8;
    const u16* bptr3 = Xb + (size_t)(n0 + 3 * 16 + l16) * C2 + lq * 8;
    const float* wrowc = Wc + (size_t)(ot * 16 + l16) * 128 + lq * 8;
    const float* wrowg = Wg + (size_t)(ot * 16 + l16) * 128 + lq * 8;

    f32x4 acc0 = {0.f, 0.f, 0.f, 0.f};
    f32x4 acc1 = {0.f, 0.f, 0.f, 0.f};
    f32x4 acc2 = {0.f, 0.f, 0.f, 0.f};
    f32x4 acc3 = {0.f, 0.f, 0.f, 0.f};
    #pragma unroll
    for (int kk = 0; kk < 8; ++kk) {
        const float* ws = (kk < 4) ? (wrowc + kk * 32) : (wrowg + (kk - 4) * 32);
        float4 wa = *(const float4*)ws;
        float4 wb = *(const float4*)(ws + 4);
        bf16x8 a;
        a[0] = (short)f2bf(wa.x); a[1] = (short)f2bf(wa.y);
        a[2] = (short)f2bf(wa.z); a[3] = (short)f2bf(wa.w);
        a[4] = (short)f2bf(wb.x); a[5] = (short)f2bf(wb.y);
        a[6] = (short)f2bf(wb.z); a[7] = (short)f2bf(wb.w);
        bf16x8 b0 = *(const bf16x8*)(bptr0 + kk * 32);
        bf16x8 b1 = *(const bf16x8*)(bptr1 + kk * 32);
        bf16x8 b2 = *(const bf16x8*)(bptr2 + kk * 32);
        bf16x8 b3 = *(const bf16x8*)(bptr3 + kk * 32);
        acc0 = __builtin_amdgcn_mfma_f32_16x16x32_bf16(a, b0, acc0, 0, 0, 0);
        acc1 = __builtin_amdgcn_mfma_f32_16x16x32_bf16(a, b1, acc1, 0, 0, 0);
        acc2 = __builtin_amdgcn_mfma_f32_16x16x32_bf16(a, b2, acc2, 0, 0, 0);
        acc3 = __builtin_amdgcn_mfma_f32_16x16x32_bf16(a, b3, acc3, 0, 0, 0);
    }

    const float inv21 = 1.0f / 21.0f;
    float bias[4];
    #pragma unroll
    for (int r = 0; r < 4; ++r) {
        int o = ot * 16 + lq * 4 + r;
        bias[r] = bc[o] + 20.f * bg[o];
    }
    const float* pb = pts + (size_t)b * C * N;
    float* ob = out + (size_t)b * C * N;
    f32x4 accs[4] = {acc0, acc1, acc2, acc3};
    #pragma unroll
    for (int t = 0; t < 4; ++t) {
        int n = n0 + t * 16 + l16;
        #pragma unroll
        for (int r = 0; r < 4; ++r) {
            int o = ot * 16 + lq * 4 + r;
            ob[(size_t)o * N + n] =
                (accs[t][r] + bias[r]) * inv21 + pb[(size_t)o * N + n];
        }
    }
}

// ---------------------------------------------------------------------------
extern "C" void kernel_launch(void* const* d_in, const int* in_sizes, int n_in,
                              void* d_out, int out_size, void* d_ws, size_t ws_size,
                              hipStream_t stream) {
    const float* xyz = (const float*)d_in[0];
    const float* pts = (const float*)d_in[1];
    const float* Wc  = (const float*)d_in[2];
    const float* bc  = (const float*)d_in[3];
    const float* Wg  = (const float*)d_in[4];
    const float* bg  = (const float*)d_in[5];
    float* out = (float*)d_out;

    u16* X = (u16*)d_ws;                              // B*N*C2 bf16 = 16 MB
    float4* cand = (float4*)((char*)d_ws +
                             (size_t)B * N * C2 * sizeof(u16));  // +512 KB

    k_transpose_lrelu<<<dim3(N / 32, C / 32, B), dim3(32, 8), 0, stream>>>(
        pts, X, xyz, cand);
    k_knn_gather<<<dim3(N / 64, B), dim3(256), 0, stream>>>(cand, X);
    k_gemm_mfma<<<dim3(1024), dim3(256), 0, stream>>>(X, Wc, Wg, pts, bc, bg, out);
}

// Round 6
// 327.531 us; speedup vs baseline: 1.0290x; 1.0290x over previous
//
#include <hip/hip_runtime.h>

// Problem constants
#define B 8
#define N 4096
#define C 128
#define C2 256          // K-dim of fused GEMM: [ptl | s]
#define KNN 21          // top-(K+1), drop nearest
#define CAP 22          // per-lane append buffer capacity (slots 0..21)

typedef unsigned long long u64;
typedef unsigned int u32;
typedef unsigned short u16;

typedef __attribute__((ext_vector_type(8))) short bf16x8;
typedef __attribute__((ext_vector_type(4))) float f32x4;

__device__ __forceinline__ float bf2f(u16 u) {
    return __uint_as_float(((u32)u) << 16);
}
__device__ __forceinline__ u16 f2bf(float f) {  // round-to-nearest-even
    u32 x = __float_as_uint(f);
    return (u16)((x + 0x7FFFu + ((x >> 16) & 1u)) >> 16);
}

// ---------------------------------------------------------------------------
// K1: transpose + leaky_relu: points (B,C,N) f32 -> X[b][n][c] (c<128) bf16.
// Also prepacks cand[b][m] = float4(x, y, z, sq_norm) once per point (same
// __fmul_rn/__fadd_rn sequence the KNN staging used inline -> bit-identical).
// ---------------------------------------------------------------------------
__global__ __launch_bounds__(256) void k_transpose_lrelu(
        const float* __restrict__ pts, u16* __restrict__ X,
        const float* __restrict__ xyz, float4* __restrict__ cand) {
    __shared__ u16 tile[32][33];
    int b  = blockIdx.z;
    int c0 = blockIdx.y * 32;
    int n0 = blockIdx.x * 32;
    int tx = threadIdx.x, ty = threadIdx.y;   // 32 x 8

    if (blockIdx.y == 0 && ty == 0) {         // prepack: 32 lanes, 32 points
        int n = n0 + tx;
        const float* xz = xyz + (size_t)b * 3 * N;
        float x = xz[n], y = xz[N + n], z = xz[2 * N + n];
        float sn = __fadd_rn(__fadd_rn(__fmul_rn(x, x), __fmul_rn(y, y)),
                             __fmul_rn(z, z));
        cand[(size_t)b * N + n] = make_float4(x, y, z, sn);
    }

    const float* src = pts + (size_t)b * C * N;
    #pragma unroll
    for (int i = 0; i < 32; i += 8) {
        float v = src[(size_t)(c0 + ty + i) * N + n0 + tx];
        if (v < 0.f) v = __fmul_rn(v, 0.01f);
        tile[ty + i][tx] = f2bf(v);
    }
    __syncthreads();
    u16* dst = X + (size_t)b * N * C2;
    #pragma unroll
    for (int i = 0; i < 32; i += 8) {
        dst[(size_t)(n0 + ty + i) * C2 + (c0 + tx)] = tile[tx][ty + i];
    }
}

// ---------------------------------------------------------------------------
// K2: exact KNN (top-21 by (sq, idx), drop min) + neighbor-feature gather-sum.
// r3 structure (S=4, per-candidate loop, CAP 22, trigger 15, merge, gather
// identical) + float keys (u32 transform only at merge-pack) + PER-SC shared
// cross-wave threshold:
//   Each wave publishes its key[20] per query to sthr[4][64] in compact.
//   Once per sc (4x total, right after the staging waitcnt -- NOT per group:
//   r5 proved per-group volatile reads put ~120cy LDS latency on the cnt
//   dependency chain, +57us), each wave reads smin = min of the other 3
//   waves' 21st keys and additionally rejects sq > smin during the scan.
//   Correctness: sq > (some wave's current 21st) => >=21 union elements
//   strictly smaller => not in union top-21. Equality kept ('<='): a tied
//   cross-wave candidate can win on idx. Own threshold stays strict '<'
//   (in-wave later idx loses ties). Staleness is conservative (thresholds
//   only decrease). volatile reads prevent hoisting out of the sc loop.
// ---------------------------------------------------------------------------
__global__ __launch_bounds__(256) void k_knn_gather(
        const float4* __restrict__ cand, u16* __restrict__ X) {
    __shared__ __align__(16) char lds[52224];
    float4* stg  = (float4*)lds;                      // [4][288]  18432 B
    u32*    kbuf = (u32*)(lds + 18432);               // [CAP][256] 22528 B
    u16*    ibuf = (u16*)(lds + 18432 + 22528);       // [CAP][256] 11264 B
    u64*    mg   = (u64*)lds;                         // [256][21]  43008 B (phase B)
    __shared__ u16 win[64 * KNN];
    __shared__ float sthr[4][64];                     // per-(wave,query) 21st key

    int tid = threadIdx.x;
    int w = tid >> 6, l = tid & 63;
    int b = blockIdx.y;
    int n0 = blockIdx.x * 64;
    int nq = n0 + l;

    const float4* candb = cand + (size_t)b * N;
    float4 cq = candb[nq];                            // query point (coalesced)
    float qx = cq.x, qy = cq.y, qz = cq.z, snq = cq.w;

    float key[KNN];
    u32 idx[KNN];
    #pragma unroll
    for (int i = 0; i < KNN; ++i) { key[i] = __builtin_inff(); idx[i] = 0u; }
    int cnt = 0;
    float thr = __builtin_inff();

    sthr[w][l] = __builtin_inff();                    // init shared thresholds
    __syncthreads();
    volatile float* vsthr = &sthr[0][0];              // force per-sc reload

    auto compact = [&]() {
        #pragma unroll 1
        for (int i = 0; i < CAP; ++i) {
            if (__ballot(i < cnt) == 0ull) break;
            float kv = __uint_as_float(kbuf[i * 256 + tid]);
            u32 iv = ibuf[i * 256 + tid];
            bool ins = (i < cnt) && (kv < key[20]);   // strict: ties keep old
            if (__ballot(ins) != 0ull) {
                key[20] = ins ? kv : key[20];
                idx[20] = ins ? iv : idx[20];
                #pragma unroll
                for (int t = 19; t >= 0; --t) {       // stable bubble (strict >)
                    bool sw = key[t] > key[t + 1];
                    float ka = sw ? key[t + 1] : key[t];
                    float kz = sw ? key[t] : key[t + 1];
                    u32 ia = sw ? idx[t + 1] : idx[t];
                    u32 iz = sw ? idx[t] : idx[t + 1];
                    key[t] = ka; key[t + 1] = kz;
                    idx[t] = ia; idx[t + 1] = iz;
                }
            }
        }
        cnt = 0;
        thr = key[20];
        sthr[w][l] = key[20];                         // publish (race-benign)
    };

    float4* mystg = stg + w * 288;
    int wl = l + (l >> 3);                            // padded staging index
    int o1 = ((w + 1) & 3) * 64 + l;                  // other waves' slots
    int o2 = ((w + 2) & 3) * 64 + l;
    int o3 = ((w + 3) & 3) * 64 + l;

    for (int sc = 0; sc < 4; ++sc) {
        int m0 = w * 1024 + sc * 256;
        // stage 256 candidates from prepacked cand (coalesced float4)
        float4 v0 = candb[m0 + l];
        float4 v1 = candb[m0 + l + 64];
        float4 v2 = candb[m0 + l + 128];
        float4 v3 = candb[m0 + l + 192];
        mystg[wl]       = v0;                         // conflict-free writes
        mystg[wl + 72]  = v1;
        mystg[wl + 144] = v2;
        mystg[wl + 216] = v3;
        asm volatile("s_waitcnt lgkmcnt(0)" ::: "memory");
        float smin = fminf(fminf(vsthr[o1], vsthr[o2]), vsthr[o3]);  // per-sc
        for (int cc = 0; cc < 256; cc += 8) {
            int base = cc + (cc >> 3);                // wave-uniform padded base
            #pragma unroll
            for (int j = 0; j < 8; ++j) {
                float4 cp = mystg[base + j];          // wave-broadcast read
                int m = m0 + cc + j;
                float dot = __fadd_rn(__fadd_rn(__fmul_rn(qx, cp.x),
                                                __fmul_rn(qy, cp.y)),
                                      __fmul_rn(qz, cp.z));
                float sq = __fadd_rn(__fsub_rn(snq, __fadd_rn(dot, dot)), cp.w);
                kbuf[cnt * 256 + tid] = __float_as_uint(sq);  // uncond append
                ibuf[cnt * 256 + tid] = (u16)m;
                cnt += ((sq < thr) && (sq <= smin));  // own strict, shared <=
            }
            if (__ballot(cnt >= 15) != 0ull) compact();
        }
    }
    compact();

    __syncthreads();                                  // phase-A buffers dead
    #pragma unroll
    for (int j = 0; j < KNN; ++j) {                   // monotone f32 -> u32
        u32 bits = __float_as_uint(key[j]);
        u32 kb2 = bits ^ (0x80000000u | (u32)(((int)bits) >> 31));
        mg[(w * 64 + l) * KNN + j] = ((u64)kb2 << 32) | (u64)idx[j];
    }
    __syncthreads();

    if (w == 0) {                                     // 4-way merge per query
        int p0 = 0, p1 = 0, p2 = 0, p3 = 0;
        for (int j = 0; j < KNN; ++j) {
            u64 c0 = mg[(0 * 64 + l) * KNN + p0];
            u64 c1 = mg[(1 * 64 + l) * KNN + p1];
            u64 c2 = mg[(2 * 64 + l) * KNN + p2];
            u64 c3 = mg[(3 * 64 + l) * KNN + p3];
            u64 m01 = c0 < c1 ? c0 : c1; int s01 = c0 < c1 ? 0 : 1;
            u64 m23 = c2 < c3 ? c2 : c3; int s23 = c2 < c3 ? 2 : 3;
            u64 mm = m01 < m23 ? m01 : m23;
            int sel = m01 < m23 ? s01 : s23;
            win[l * KNN + j] = (u16)(mm & 0xFFFFu);
            p0 += (sel == 0); p1 += (sel == 1); p2 += (sel == 2); p3 += (sel == 3);
        }
    }
    __syncthreads();

    // gather-sum: wave w handles 16 queries; lane covers channels 2l, 2l+1
    const u16* Xb = X + (size_t)b * N * C2;
    for (int qq = 0; qq < 16; ++qq) {
        int q = w * 16 + qq;
        float f0 = 0.f, f1 = 0.f;
        #pragma unroll
        for (int j = 1; j < KNN; ++j) {               // skip nearest (j=0)
            int m = win[q * KNN + j];
            u32 u2 = *(const u32*)(Xb + (size_t)m * C2 + 2 * l);
            f0 += bf2f((u16)(u2 & 0xFFFFu));
            f1 += bf2f((u16)(u2 >> 16));
        }
        u16* dst = X + ((size_t)b * N + n0 + q) * C2 + 128 + 2 * l;
        *(u32*)dst = ((u32)f2bf(f1) << 16) | (u32)f2bf(f0);
    }
}

// ---------------------------------------------------------------------------
// K3: MFMA GEMM. out[b][o][n] = (W[o][:].X[b][n][:] + bc[o]+20bg[o])/21 + pts.
// RESTRUCTURED: one block per (b, 64-row n-panel), grid 512. The 64x256 bf16
// X panel (32KB) is staged ONCE, coalesced, into LDS (row pad 264 u16 = 528B:
// 16B-aligned, bank stride 132 -> 2-way = free). Previously each panel was
// fetched by 8 waves in 2 blocks via 16B loads at 512B stride (~4x line
// overfetch). 4 waves x 2 o-tiles each; B-frags ds_read_b128, shared across
// the o-pair. Identical MFMA math / rounding / output map as before.
// C/D map: col=lane&15 (n), row=(lane>>4)*4+reg (o)  [m89-verified]
// ---------------------------------------------------------------------------
__global__ __launch_bounds__(256) void k_gemm_mfma(
        const u16* __restrict__ X, const float* __restrict__ Wc,
        const float* __restrict__ Wg, const float* __restrict__ pts,
        const float* __restrict__ bc, const float* __restrict__ bg,
        float* __restrict__ out) {
    __shared__ u16 xs[64][264];                       // 33792 B, padded rows
    int bid = blockIdx.x;                             // 0..511
    int b  = bid >> 6;
    int n0 = (bid & 63) * 64;
    int tid = threadIdx.x;

    const u16* Xb = X + (size_t)b * N * C2;
    #pragma unroll
    for (int it = 0; it < 8; ++it) {                  // stage panel, coalesced
        int t = it * 256 + tid;                       // 0..2047
        int r = t >> 5, cch = t & 31;                 // row, 16B chunk
        *(bf16x8*)(&xs[r][cch * 8]) =
            *(const bf16x8*)(Xb + (size_t)(n0 + r) * C2 + cch * 8);
    }
    __syncthreads();

    int w = tid >> 6, lane = tid & 63;
    int l16 = lane & 15, lq = lane >> 4;
    // wave w handles o-tiles 2w, 2w+1 (o rows w*32 .. w*32+31)
    const float* wc0 = Wc + (size_t)(w * 32 + l16) * 128 + lq * 8;
    const float* wc1 = Wc + (size_t)(w * 32 + 16 + l16) * 128 + lq * 8;
    const float* wg0 = Wg + (size_t)(w * 32 + l16) * 128 + lq * 8;
    const float* wg1 = Wg + (size_t)(w * 32 + 16 + l16) * 128 + lq * 8;

    f32x4 acc[2][4];
    #pragma unroll
    for (int oo = 0; oo < 2; ++oo)
        #pragma unroll
        for (int t = 0; t < 4; ++t)
            acc[oo][t] = (f32x4){0.f, 0.f, 0.f, 0.f};

    #pragma unroll
    for (int kk = 0; kk < 8; ++kk) {
        const float* s0 = (kk < 4) ? (wc0 + kk * 32) : (wg0 + (kk - 4) * 32);
        const float* s1 = (kk < 4) ? (wc1 + kk * 32) : (wg1 + (kk - 4) * 32);
        float4 wa0 = *(const float4*)s0, wb0 = *(const float4*)(s0 + 4);
        float4 wa1 = *(const float4*)s1, wb1 = *(const float4*)(s1 + 4);
        bf16x8 a0, a1;
        a0[0] = (short)f2bf(wa0.x); a0[1] = (short)f2bf(wa0.y);
        a0[2] = (short)f2bf(wa0.z); a0[3] = (short)f2bf(wa0.w);
        a0[4] = (short)f2bf(wb0.x); a0[5] = (short)f2bf(wb0.y);
        a0[6] = (short)f2bf(wb0.z); a0[7] = (short)f2bf(wb0.w);
        a1[0] = (short)f2bf(wa1.x); a1[1] = (short)f2bf(wa1.y);
        a1[2] = (short)f2bf(wa1.z); a1[3] = (short)f2bf(wa1.w);
        a1[4] = (short)f2bf(wb1.x); a1[5] = (short)f2bf(wb1.y);
        a1[6] = (short)f2bf(wb1.z); a1[7] = (short)f2bf(wb1.w);
        #pragma unroll
        for (int t = 0; t < 4; ++t) {
            bf16x8 bt = *(const bf16x8*)(&xs[t * 16 + l16][lq * 8 + kk * 32]);
            acc[0][t] = __builtin_amdgcn_mfma_f32_16x16x32_bf16(a0, bt,
                                                                acc[0][t], 0, 0, 0);
            acc[1][t] = __builtin_amdgcn_mfma_f32_16x16x32_bf16(a1, bt,
                                                                acc[1][t], 0, 0, 0);
        }
    }

    const float inv21 = 1.0f / 21.0f;
    const float* pb = pts + (size_t)b * C * N;
    float* ob = out + (size_t)b * C * N;
    #pragma unroll
    for (int oo = 0; oo < 2; ++oo) {
        float bias[4];
        #pragma unroll
        for (int r = 0; r < 4; ++r) {
            int o = w * 32 + oo * 16 + lq * 4 + r;
            bias[r] = bc[o] + 20.f * bg[o];
        }
        #pragma unroll
        for (int t = 0; t < 4; ++t) {
            int n = n0 + t * 16 + l16;
            #pragma unroll
            for (int r = 0; r < 4; ++r) {
                int o = w * 32 + oo * 16 + lq * 4 + r;
                ob[(size_t)o * N + n] =
                    (acc[oo][t][r] + bias[r]) * inv21 + pb[(size_t)o * N + n];
            }
        }
    }
}

// ---------------------------------------------------------------------------
extern "C" void kernel_launch(void* const* d_in, const int* in_sizes, int n_in,
                              void* d_out, int out_size, void* d_ws, size_t ws_size,
                              hipStream_t stream) {
    const float* xyz = (const float*)d_in[0];
    const float* pts = (const float*)d_in[1];
    const float* Wc  = (const float*)d_in[2];
    const float* bc  = (const float*)d_in[3];
    const float* Wg  = (const float*)d_in[4];
    const float* bg  = (const float*)d_in[5];
    float* out = (float*)d_out;

    u16* X = (u16*)d_ws;                              // B*N*C2 bf16 = 16 MB
    float4* cand = (float4*)((char*)d_ws +
                             (size_t)B * N * C2 * sizeof(u16));  // +512 KB

    k_transpose_lrelu<<<dim3(N / 32, C / 32, B), dim3(32, 8), 0, stream>>>(
        pts, X, xyz, cand);
    k_knn_gather<<<dim3(N / 64, B), dim3(256), 0, stream>>>(cand, X);
    k_gemm_mfma<<<dim3(512), dim3(256), 0, stream>>>(X, Wc, Wg, pts, bc, bg, out);
}

// Round 7
// 277.820 us; speedup vs baseline: 1.2131x; 1.1789x over previous
//
#include <hip/hip_runtime.h>

// Problem constants
#define B 8
#define N 4096
#define C 128
#define C2 256          // K-dim of fused GEMM: [ptl | s]
#define KNN 21          // top-(K+1), drop nearest
#define CAP 22          // per-lane append buffer capacity (slots 0..21)

typedef unsigned long long u64;
typedef unsigned int u32;
typedef unsigned short u16;

typedef __attribute__((ext_vector_type(8))) short bf16x8;
typedef __attribute__((ext_vector_type(4))) float f32x4;

__device__ __forceinline__ float bf2f(u16 u) {
    return __uint_as_float(((u32)u) << 16);
}
__device__ __forceinline__ u16 f2bf(float f) {  // round-to-nearest-even
    u32 x = __float_as_uint(f);
    return (u16)((x + 0x7FFFu + ((x >> 16) & 1u)) >> 16);
}

// ---------------------------------------------------------------------------
// K1: transpose + leaky_relu: points (B,C,N) f32 -> X[b][n][c] (c<128) bf16.
// Also prepacks cand[b][m] = float4(x, y, z, sq_norm) once per point (same
// __fmul_rn/__fadd_rn sequence the KNN staging used inline -> bit-identical).
// ---------------------------------------------------------------------------
__global__ __launch_bounds__(256) void k_transpose_lrelu(
        const float* __restrict__ pts, u16* __restrict__ X,
        const float* __restrict__ xyz, float4* __restrict__ cand) {
    __shared__ u16 tile[32][33];
    int b  = blockIdx.z;
    int c0 = blockIdx.y * 32;
    int n0 = blockIdx.x * 32;
    int tx = threadIdx.x, ty = threadIdx.y;   // 32 x 8

    if (blockIdx.y == 0 && ty == 0) {         // prepack: 32 lanes, 32 points
        int n = n0 + tx;
        const float* xz = xyz + (size_t)b * 3 * N;
        float x = xz[n], y = xz[N + n], z = xz[2 * N + n];
        float sn = __fadd_rn(__fadd_rn(__fmul_rn(x, x), __fmul_rn(y, y)),
                             __fmul_rn(z, z));
        cand[(size_t)b * N + n] = make_float4(x, y, z, sn);
    }

    const float* src = pts + (size_t)b * C * N;
    #pragma unroll
    for (int i = 0; i < 32; i += 8) {
        float v = src[(size_t)(c0 + ty + i) * N + n0 + tx];
        if (v < 0.f) v = __fmul_rn(v, 0.01f);
        tile[ty + i][tx] = f2bf(v);
    }
    __syncthreads();
    u16* dst = X + (size_t)b * N * C2;
    #pragma unroll
    for (int i = 0; i < 32; i += 8) {
        dst[(size_t)(n0 + ty + i) * C2 + (c0 + tx)] = tile[tx][ty + i];
    }
}

// ---------------------------------------------------------------------------
// K2: exact KNN (top-21 by (sq, idx), drop min) + neighbor-feature gather-sum.
// r3's proven loop BYTE-FOR-BYTE (u32 sortable keys in scan+compact -- f32
// keys cost +55us of stall, measured 2x in r2/r5/r6) + ONE minimal graft:
// u32 SHARED CROSS-WAVE THRESHOLD.
//   compact publishes key[20] to sthr[4][64]; once per sc (in the staging-
//   wait shadow, NOT per group -- r5) each wave reads the other 3 waves'
//   values (3 volatile LDS reads + 2 v_min_u32) and the append condition
//   gains one compare: (kb < thr) & (kb <= smin).
//   Correctness: kb > (some wave's current 21st key) => >=21 union elements
//   strictly smaller => not in union top-21 => safe to drop. '<=' on the
//   shared bound keeps cross-wave ties (tied candidate can win on idx);
//   own bound stays strict '<' (in-wave later idx loses ties). Staleness is
//   conservative (thresholds only decrease). u32 transform is monotone =>
//   compares equivalent to sq compares.
// ---------------------------------------------------------------------------
__global__ __launch_bounds__(256) void k_knn_gather(
        const float4* __restrict__ cand, u16* __restrict__ X) {
    __shared__ __align__(16) char lds[52224];
    float4* stg  = (float4*)lds;                      // [4][288]  18432 B
    u32*    kbuf = (u32*)(lds + 18432);               // [CAP][256] 22528 B
    u16*    ibuf = (u16*)(lds + 18432 + 22528);       // [CAP][256] 11264 B
    u64*    mg   = (u64*)lds;                         // [256][21]  43008 B (phase B)
    __shared__ u16 win[64 * KNN];
    __shared__ u32 sthr[4][64];                       // per-(wave,query) 21st key

    int tid = threadIdx.x;
    int w = tid >> 6, l = tid & 63;
    int b = blockIdx.y;
    int n0 = blockIdx.x * 64;
    int nq = n0 + l;

    const float4* candb = cand + (size_t)b * N;
    float4 cq = candb[nq];                            // query point (coalesced)
    float qx = cq.x, qy = cq.y, qz = cq.z, snq = cq.w;

    u32 key[KNN], idx[KNN];
    #pragma unroll
    for (int i = 0; i < KNN; ++i) { key[i] = 0xFFFFFFFFu; idx[i] = 0u; }
    int cnt = 0;
    u32 thr = 0xFFFFFFFFu;

    sthr[w][l] = 0xFFFFFFFFu;                         // init shared thresholds
    __syncthreads();
    volatile u32* vsthr = &sthr[0][0];                // force per-sc reload

    auto compact = [&]() {
        #pragma unroll 1
        for (int i = 0; i < CAP; ++i) {
            if (__ballot(i < cnt) == 0ull) break;
            u32 kv = kbuf[i * 256 + tid];
            u32 iv = ibuf[i * 256 + tid];
            bool ins = (i < cnt) && (kv < key[20]);   // strict: ties keep old
            if (__ballot(ins) != 0ull) {
                key[20] = ins ? kv : key[20];
                idx[20] = ins ? iv : idx[20];
                #pragma unroll
                for (int t = 19; t >= 0; --t) {       // stable bubble (strict >)
                    bool sw = key[t] > key[t + 1];
                    u32 ka = sw ? key[t + 1] : key[t];
                    u32 kz = sw ? key[t] : key[t + 1];
                    u32 ia = sw ? idx[t + 1] : idx[t];
                    u32 iz = sw ? idx[t] : idx[t + 1];
                    key[t] = ka; key[t + 1] = kz;
                    idx[t] = ia; idx[t + 1] = iz;
                }
            }
        }
        cnt = 0;
        thr = key[20];
        sthr[w][l] = key[20];                         // publish (race-benign)
    };

    float4* mystg = stg + w * 288;
    int wl = l + (l >> 3);                            // padded staging index
    int o1 = ((w + 1) & 3) * 64 + l;                  // other waves' slots
    int o2 = ((w + 2) & 3) * 64 + l;
    int o3 = ((w + 3) & 3) * 64 + l;

    for (int sc = 0; sc < 4; ++sc) {
        int m0 = w * 1024 + sc * 256;
        // stage 256 candidates from prepacked cand (coalesced float4)
        float4 v0 = candb[m0 + l];
        float4 v1 = candb[m0 + l + 64];
        float4 v2 = candb[m0 + l + 128];
        float4 v3 = candb[m0 + l + 192];
        mystg[wl]       = v0;                         // conflict-free writes
        mystg[wl + 72]  = v1;
        mystg[wl + 144] = v2;
        mystg[wl + 216] = v3;
        asm volatile("s_waitcnt lgkmcnt(0)" ::: "memory");
        u32 smin = min(min(vsthr[o1], vsthr[o2]), vsthr[o3]);  // per-sc refresh
        for (int cc = 0; cc < 256; cc += 8) {
            int base = cc + (cc >> 3);                // wave-uniform padded base
            #pragma unroll
            for (int j = 0; j < 8; ++j) {
                float4 cp = mystg[base + j];          // wave-broadcast read
                int m = m0 + cc + j;
                float dot = __fadd_rn(__fadd_rn(__fmul_rn(qx, cp.x),
                                                __fmul_rn(qy, cp.y)),
                                      __fmul_rn(qz, cp.z));
                float sq = __fadd_rn(__fsub_rn(snq, __fadd_rn(dot, dot)), cp.w);
                u32 bits = __float_as_uint(sq);
                u32 kb = bits ^ (0x80000000u | (u32)(((int)bits) >> 31));
                kbuf[cnt * 256 + tid] = kb;           // unconditional append
                ibuf[cnt * 256 + tid] = (u16)m;
                cnt += (kb < thr) & (kb <= smin);     // own strict, shared <=
            }
            if (__ballot(cnt >= 15) != 0ull) compact();
        }
    }
    compact();

    __syncthreads();                                  // phase-A buffers dead
    #pragma unroll
    for (int j = 0; j < KNN; ++j)
        mg[(w * 64 + l) * KNN + j] = ((u64)key[j] << 32) | (u64)idx[j];
    __syncthreads();

    if (w == 0) {                                     // 4-way merge per query
        int p0 = 0, p1 = 0, p2 = 0, p3 = 0;
        for (int j = 0; j < KNN; ++j) {
            u64 c0 = mg[(0 * 64 + l) * KNN + p0];
            u64 c1 = mg[(1 * 64 + l) * KNN + p1];
            u64 c2 = mg[(2 * 64 + l) * KNN + p2];
            u64 c3 = mg[(3 * 64 + l) * KNN + p3];
            u64 m01 = c0 < c1 ? c0 : c1; int s01 = c0 < c1 ? 0 : 1;
            u64 m23 = c2 < c3 ? c2 : c3; int s23 = c2 < c3 ? 2 : 3;
            u64 mm = m01 < m23 ? m01 : m23;
            int sel = m01 < m23 ? s01 : s23;
            win[l * KNN + j] = (u16)(mm & 0xFFFFu);
            p0 += (sel == 0); p1 += (sel == 1); p2 += (sel == 2); p3 += (sel == 3);
        }
    }
    __syncthreads();

    // gather-sum: wave w handles 16 queries; lane covers channels 2l, 2l+1
    const u16* Xb = X + (size_t)b * N * C2;
    for (int qq = 0; qq < 16; ++qq) {
        int q = w * 16 + qq;
        float f0 = 0.f, f1 = 0.f;
        #pragma unroll
        for (int j = 1; j < KNN; ++j) {               // skip nearest (j=0)
            int m = win[q * KNN + j];
            u32 u2 = *(const u32*)(Xb + (size_t)m * C2 + 2 * l);
            f0 += bf2f((u16)(u2 & 0xFFFFu));
            f1 += bf2f((u16)(u2 >> 16));
        }
        u16* dst = X + ((size_t)b * N + n0 + q) * C2 + 128 + 2 * l;
        *(u32*)dst = ((u32)f2bf(f1) << 16) | (u32)f2bf(f0);
    }
}

// ---------------------------------------------------------------------------
// K3: MFMA GEMM. out[b][o][n] = (W[o][:].X[b][n][:] + bc[o]+20bg[o])/21 + pts.
// One block per (b, 64-row n-panel), grid 512. The 64x256 bf16 X panel (32KB)
// staged ONCE, coalesced, into LDS (row pad 264 u16 = 528B: 16B-aligned, bank
// stride 132 -> 2-way = free). 4 waves x 2 o-tiles each; B-frags ds_read_b128
// shared across the o-pair. Identical MFMA math / rounding / output map.
// C/D map: col=lane&15 (n), row=(lane>>4)*4+reg (o)  [m89-verified]
// ---------------------------------------------------------------------------
__global__ __launch_bounds__(256) void k_gemm_mfma(
        const u16* __restrict__ X, const float* __restrict__ Wc,
        const float* __restrict__ Wg, const float* __restrict__ pts,
        const float* __restrict__ bc, const float* __restrict__ bg,
        float* __restrict__ out) {
    __shared__ u16 xs[64][264];                       // 33792 B, padded rows
    int bid = blockIdx.x;                             // 0..511
    int b  = bid >> 6;
    int n0 = (bid & 63) * 64;
    int tid = threadIdx.x;

    const u16* Xb = X + (size_t)b * N * C2;
    #pragma unroll
    for (int it = 0; it < 8; ++it) {                  // stage panel, coalesced
        int t = it * 256 + tid;                       // 0..2047
        int r = t >> 5, cch = t & 31;                 // row, 16B chunk
        *(bf16x8*)(&xs[r][cch * 8]) =
            *(const bf16x8*)(Xb + (size_t)(n0 + r) * C2 + cch * 8);
    }
    __syncthreads();

    int w = tid >> 6, lane = tid & 63;
    int l16 = lane & 15, lq = lane >> 4;
    // wave w handles o-tiles 2w, 2w+1 (o rows w*32 .. w*32+31)
    const float* wc0 = Wc + (size_t)(w * 32 + l16) * 128 + lq * 8;
    const float* wc1 = Wc + (size_t)(w * 32 + 16 + l16) * 128 + lq * 8;
    const float* wg0 = Wg + (size_t)(w * 32 + l16) * 128 + lq * 8;
    const float* wg1 = Wg + (size_t)(w * 32 + 16 + l16) * 128 + lq * 8;

    f32x4 acc[2][4];
    #pragma unroll
    for (int oo = 0; oo < 2; ++oo)
        #pragma unroll
        for (int t = 0; t < 4; ++t)
            acc[oo][t] = (f32x4){0.f, 0.f, 0.f, 0.f};

    #pragma unroll
    for (int kk = 0; kk < 8; ++kk) {
        const float* s0 = (kk < 4) ? (wc0 + kk * 32) : (wg0 + (kk - 4) * 32);
        const float* s1 = (kk < 4) ? (wc1 + kk * 32) : (wg1 + (kk - 4) * 32);
        float4 wa0 = *(const float4*)s0, wb0 = *(const float4*)(s0 + 4);
        float4 wa1 = *(const float4*)s1, wb1 = *(const float4*)(s1 + 4);
        bf16x8 a0, a1;
        a0[0] = (short)f2bf(wa0.x); a0[1] = (short)f2bf(wa0.y);
        a0[2] = (short)f2bf(wa0.z); a0[3] = (short)f2bf(wa0.w);
        a0[4] = (short)f2bf(wb0.x); a0[5] = (short)f2bf(wb0.y);
        a0[6] = (short)f2bf(wb0.z); a0[7] = (short)f2bf(wb0.w);
        a1[0] = (short)f2bf(wa1.x); a1[1] = (short)f2bf(wa1.y);
        a1[2] = (short)f2bf(wa1.z); a1[3] = (short)f2bf(wa1.w);
        a1[4] = (short)f2bf(wb1.x); a1[5] = (short)f2bf(wb1.y);
        a1[6] = (short)f2bf(wb1.z); a1[7] = (short)f2bf(wb1.w);
        #pragma unroll
        for (int t = 0; t < 4; ++t) {
            bf16x8 bt = *(const bf16x8*)(&xs[t * 16 + l16][lq * 8 + kk * 32]);
            acc[0][t] = __builtin_amdgcn_mfma_f32_16x16x32_bf16(a0, bt,
                                                                acc[0][t], 0, 0, 0);
            acc[1][t] = __builtin_amdgcn_mfma_f32_16x16x32_bf16(a1, bt,
                                                                acc[1][t], 0, 0, 0);
        }
    }

    const float inv21 = 1.0f / 21.0f;
    const float* pb = pts + (size_t)b * C * N;
    float* ob = out + (size_t)b * C * N;
    #pragma unroll
    for (int oo = 0; oo < 2; ++oo) {
        float bias[4];
        #pragma unroll
        for (int r = 0; r < 4; ++r) {
            int o = w * 32 + oo * 16 + lq * 4 + r;
            bias[r] = bc[o] + 20.f * bg[o];
        }
        #pragma unroll
        for (int t = 0; t < 4; ++t) {
            int n = n0 + t * 16 + l16;
            #pragma unroll
            for (int r = 0; r < 4; ++r) {
                int o = w * 32 + oo * 16 + lq * 4 + r;
                ob[(size_t)o * N + n] =
                    (acc[oo][t][r] + bias[r]) * inv21 + pb[(size_t)o * N + n];
            }
        }
    }
}

// ---------------------------------------------------------------------------
extern "C" void kernel_launch(void* const* d_in, const int* in_sizes, int n_in,
                              void* d_out, int out_size, void* d_ws, size_t ws_size,
                              hipStream_t stream) {
    const float* xyz = (const float*)d_in[0];
    const float* pts = (const float*)d_in[1];
    const float* Wc  = (const float*)d_in[2];
    const float* bc  = (const float*)d_in[3];
    const float* Wg  = (const float*)d_in[4];
    const float* bg  = (const float*)d_in[5];
    float* out = (float*)d_out;

    u16* X = (u16*)d_ws;                              // B*N*C2 bf16 = 16 MB
    float4* cand = (float4*)((char*)d_ws +
                             (size_t)B * N * C2 * sizeof(u16));  // +512 KB

    k_transpose_lrelu<<<dim3(N / 32, C / 32, B), dim3(32, 8), 0, stream>>>(
        pts, X, xyz, cand);
    k_knn_gather<<<dim3(N / 64, B), dim3(256), 0, stream>>>(cand, X);
    k_gemm_mfma<<<dim3(512), dim3(256), 0, stream>>>(X, Wc, Wg, pts, bc, bg, out);
}